// Round 11
// baseline (534.197 us; speedup 1.0000x reference)
//
#include <hip/hip_runtime.h>
#include <hip/hip_bf16.h>

#define NUM_TASKS 50
#define NUM_EXPERTS 8
#define WIDTH 1024
#define FEAT 512
#define HEAD_DIM 256
#define BATCH 4096
#define XCOLS (FEAT + NUM_TASKS)   // 562

typedef unsigned short ushort_t;
typedef short bf16x8 __attribute__((ext_vector_type(8)));
typedef float f32x4 __attribute__((ext_vector_type(4)));
typedef float f32x16 __attribute__((ext_vector_type(16)));

// fp32 -> bf16 (RNE) raw bits
__device__ __forceinline__ ushort_t f2b(float f) {
    unsigned u = __float_as_uint(f);
    unsigned r = (u + 0x7fffu + ((u >> 16) & 1u)) >> 16;
    return (ushort_t)r;
}
__device__ __forceinline__ float b2f_lo(unsigned u) { return __uint_as_float(u << 16); }
__device__ __forceinline__ float b2f_hi(unsigned u) { return __uint_as_float(u & 0xffff0000u); }

__device__ __forceinline__ void async16(const ushort_t* g, ushort_t* l) {
    __builtin_amdgcn_global_load_lds(
        (const __attribute__((address_space(1))) unsigned int*)g,
        (__attribute__((address_space(3))) unsigned int*)l,
        16, 0, 0);
}

// bank-conflict-free swizzle key (r9/r10-verified: 0 conflicts)
__device__ __forceinline__ int swz(int r) { return (r & 7) ^ ((r >> 3) & 3); }

// ---------------------------------------------------------------------------
// prepx: task id + emb + x-feat bf16 conversion (merged)
// ---------------------------------------------------------------------------
__global__ void prepx_kernel(const float* __restrict__ x,
                             const float* __restrict__ W_emb,
                             const float* __restrict__ b_emb,
                             float* __restrict__ emb,
                             int* __restrict__ tids,
                             ushort_t* __restrict__ xb) {
    int b = blockIdx.x;
    int lane = threadIdx.x;  // 64
    const float* xr = x + (size_t)b * XCOLS;
    float v = 0.f;
    if (lane < NUM_TASKS) v = xr[FEAT + lane];
    unsigned long long mask = __ballot(v > 0.5f);
    int tid = __ffsll(mask) - 1;
    if (tid < 0) tid = 0;
    if (tid > NUM_TASKS - 1) tid = NUM_TASKS - 1;
    if (lane == 0) tids[b] = tid;
    if (lane < NUM_EXPERTS)
        emb[(size_t)b * NUM_EXPERTS + lane] =
            W_emb[tid * NUM_EXPERTS + lane] + b_emb[lane];
    float f[8];
    #pragma unroll
    for (int j = 0; j < 8; ++j) f[j] = xr[lane * 8 + j];
    unsigned u[4];
    #pragma unroll
    for (int j = 0; j < 4; ++j)
        u[j] = (unsigned)f2b(f[2 * j]) | ((unsigned)f2b(f[2 * j + 1]) << 16);
    *reinterpret_cast<uint4*>(xb + (size_t)b * FEAT + lane * 8) =
        make_uint4(u[0], u[1], u[2], u[3]);
}

// ---------------------------------------------------------------------------
// counting sort by task
// ---------------------------------------------------------------------------
__global__ void sort_kernel(const int* __restrict__ tids,
                            int* __restrict__ pos,
                            int* __restrict__ row_map,
                            int* __restrict__ tstart,
                            int* __restrict__ tcnt) {
    __shared__ int cnt[NUM_TASKS];
    __shared__ int start[NUM_TASKS];
    __shared__ int rank[NUM_TASKS];
    int t = threadIdx.x;
    if (t < NUM_TASKS) { cnt[t] = 0; rank[t] = 0; }
    __syncthreads();
    for (int b = t; b < BATCH; b += 256) atomicAdd(&cnt[tids[b]], 1);
    __syncthreads();
    if (t == 0) {
        int acc = 0;
        for (int k = 0; k < NUM_TASKS; ++k) { start[k] = acc; acc += cnt[k]; }
    }
    __syncthreads();
    if (t < NUM_TASKS) { tstart[t] = start[t]; tcnt[t] = cnt[t]; }
    for (int b = t; b < BATCH; b += 256) {
        int tk = tids[b];
        int p = start[tk] + atomicAdd(&rank[tk], 1);
        pos[b] = p;
        row_map[p] = b;
    }
}

// ---------------------------------------------------------------------------
// 64x64-tile transpose+convert: fp32 [z][R][C] -> bf16 [z][C][R]
// ---------------------------------------------------------------------------
__global__ __launch_bounds__(256) void conv_t64(const float* __restrict__ src,
                                                ushort_t* __restrict__ dst,
                                                int R, int C) {
    int r0 = blockIdx.x * 64, c0 = blockIdx.y * 64, z = blockIdx.z;
    __shared__ float tile[64][65];
    const float* S = src + (size_t)z * R * C;
    ushort_t* D = dst + (size_t)z * R * C;
    int t = threadIdx.x;
    const int ci4 = t & 15, ri = t >> 4;
    #pragma unroll
    for (int p = 0; p < 4; ++p) {
        int r = ri + 16 * p;
        float4 v = *reinterpret_cast<const float4*>(S + (size_t)(r0 + r) * C + c0 + ci4 * 4);
        tile[r][ci4 * 4 + 0] = v.x;
        tile[r][ci4 * 4 + 1] = v.y;
        tile[r][ci4 * 4 + 2] = v.z;
        tile[r][ci4 * 4 + 3] = v.w;
    }
    __syncthreads();
    const int co2 = t & 31, ci = t >> 5;
    #pragma unroll
    for (int p = 0; p < 8; ++p) {
        int c = ci + 8 * p;
        float a = tile[co2 * 2 + 0][c];
        float b = tile[co2 * 2 + 1][c];
        unsigned u = (unsigned)f2b(a) | ((unsigned)f2b(b) << 16);
        *reinterpret_cast<unsigned*>(D + (size_t)(c0 + c) * R + r0 + co2 * 2) = u;
    }
}

// ---------------------------------------------------------------------------
// MFMA expert-batched GEMM, 32x32x16, BM=128 BN=256 BK=64, swizzled LDS.
// 4 waves side-by-side in n: wave w owns 128m x 64n (4m x 2n MFMA tiles).
// Staged bytes/FLOP improved 1.5x vs 128x128 (round-10 L2-delivery analysis).
// ---------------------------------------------------------------------------
template <bool RELU>
__global__ __launch_bounds__(256) void mfma_gemm(
    const ushort_t* __restrict__ A, int lda, int aoff,
    const ushort_t* __restrict__ Bt,
    const float* __restrict__ bias,
    ushort_t* __restrict__ C, int K)
{
    const int m0 = blockIdx.x * 128;
    const int n0 = blockIdx.y * 256;
    const int e  = blockIdx.z;
    const int t  = threadIdx.x;
    const int l  = t & 63;

    __shared__ __align__(16) ushort_t As[128 * 64];  // 16 KB
    __shared__ __align__(16) ushort_t Bs[256 * 64];  // 32 KB

    const ushort_t* __restrict__ Ab = A + (size_t)e * aoff + (size_t)m0 * lda;
    const ushort_t* __restrict__ Bb = Bt + ((size_t)e * WIDTH + n0) * K;

    // staging: thread t -> row (t>>3), slot (t&7); loads granule (t&7)^swz(row)
    const int sr = t >> 3;                          // 0..31
    const int sk = ((t & 7) ^ swz(sr)) * 8;         // global k-element offset

    const int w  = t >> 6;                          // wave 0..3 -> n-offset w*64
    const int wn = w * 64;
    const int ra = l & 31;                          // fragment row within 32
    const int hi = l >> 5;                          // k-half (0/1)
    const int kx = swz(ra);                         // read-side key

    f32x16 acc[4][2];
    #pragma unroll
    for (int i = 0; i < 4; ++i)
        #pragma unroll
        for (int j = 0; j < 2; ++j)
            #pragma unroll
            for (int q = 0; q < 16; ++q) acc[i][j][q] = 0.f;

    for (int kt = 0; kt < K; kt += 64) {
        __syncthreads();
        #pragma unroll
        for (int p = 0; p < 4; ++p)
            async16(Ab + (size_t)(p * 32 + sr) * lda + kt + sk, &As[p * 2048 + t * 8]);
        #pragma unroll
        for (int p = 0; p < 8; ++p)
            async16(Bb + (size_t)(p * 32 + sr) * K   + kt + sk, &Bs[p * 2048 + t * 8]);
        __syncthreads();

        #pragma unroll
        for (int ks = 0; ks < 4; ++ks) {
            const int slot = ((ks * 2 + hi) ^ kx) * 8;
            bf16x8 af[4], bfr[2];
            #pragma unroll
            for (int mi = 0; mi < 4; ++mi)
                af[mi] = *reinterpret_cast<const bf16x8*>(&As[(mi * 32 + ra) * 64 + slot]);
            #pragma unroll
            for (int ni = 0; ni < 2; ++ni)
                bfr[ni] = *reinterpret_cast<const bf16x8*>(&Bs[(wn + ni * 32 + ra) * 64 + slot]);
            #pragma unroll
            for (int mi = 0; mi < 4; ++mi)
                #pragma unroll
                for (int ni = 0; ni < 2; ++ni)
                    acc[mi][ni] = __builtin_amdgcn_mfma_f32_32x32x16_bf16(
                        af[mi], bfr[ni], acc[mi][ni], 0, 0, 0);
        }
    }

    const int lrow = 4 * hi;
    #pragma unroll
    for (int mi = 0; mi < 4; ++mi) {
        #pragma unroll
        for (int ni = 0; ni < 2; ++ni) {
            int col = n0 + wn + ni * 32 + ra;
            float bv = bias[e * WIDTH + col];
            #pragma unroll
            for (int r = 0; r < 16; ++r) {
                int row = m0 + mi * 32 + 8 * (r >> 2) + lrow + (r & 3);
                float v = acc[mi][ni][r] + bv;
                if (RELU) v = fmaxf(v, 0.f);
                C[(size_t)row * (NUM_EXPERTS * WIDTH) + e * WIDTH + col] = f2b(v);
            }
        }
    }
}

// ---------------------------------------------------------------------------
// Wave-per-row register Gram-Schmidt -> bf16 feats at task-sorted slot
// ---------------------------------------------------------------------------
__device__ __forceinline__ float wave_sum(float x) {
    #pragma unroll
    for (int off = 1; off < 64; off <<= 1) x += __shfl_xor(x, off, 64);
    return x;
}
__device__ __forceinline__ void u2f8(uint4 a, float* f) {
    f[0] = b2f_lo(a.x); f[1] = b2f_hi(a.x);
    f[2] = b2f_lo(a.y); f[3] = b2f_hi(a.y);
    f[4] = b2f_lo(a.z); f[5] = b2f_hi(a.z);
    f[6] = b2f_lo(a.w); f[7] = b2f_hi(a.w);
}

__global__ __launch_bounds__(256, 1) void gs_wave_kernel(
    const ushort_t* __restrict__ eo,   // [CHUNK][8][1024] bf16
    const float* __restrict__ emb,     // [CHUNK][8]
    const int* __restrict__ pos,       // [CHUNK] global sorted slot
    ushort_t* __restrict__ featsB)     // [BATCH][1024] bf16 (sorted)
{
    const int w = threadIdx.x >> 6;
    const int l = threadIdx.x & 63;
    const int r = blockIdx.x * 4 + w;

    float v[NUM_EXPERTS][16];
    const ushort_t* row = eo + (size_t)r * (NUM_EXPERTS * WIDTH);
    #pragma unroll
    for (int e = 0; e < NUM_EXPERTS; ++e) {
        const uint4* p = reinterpret_cast<const uint4*>(row + e * WIDTH + l * 16);
        u2f8(p[0], &v[e][0]);
        u2f8(p[1], &v[e][8]);
    }

    {
        float s = 0.f;
        #pragma unroll
        for (int j = 0; j < 16; ++j) s += v[0][j] * v[0][j];
        s = wave_sum(s);
        float inv = 1.f / sqrtf(s);
        #pragma unroll
        for (int j = 0; j < 16; ++j) v[0][j] *= inv;
    }

    #pragma unroll
    for (int i = 1; i < NUM_EXPERTS; ++i) {
        float c[NUM_EXPERTS];
        #pragma unroll
        for (int jj = 0; jj < i; ++jj) {
            float p = 0.f;
            #pragma unroll
            for (int j = 0; j < 16; ++j) p += v[i][j] * v[jj][j];
            c[jj] = wave_sum(p);
        }
        float s = 0.f;
        #pragma unroll
        for (int j = 0; j < 16; ++j) {
            float wv = v[i][j];
            #pragma unroll
            for (int jj = 0; jj < i; ++jj) wv -= c[jj] * v[jj][j];
            v[i][j] = wv;
            s += wv * wv;
        }
        s = wave_sum(s);
        float inv = 1.f / sqrtf(s);
        #pragma unroll
        for (int j = 0; j < 16; ++j) v[i][j] *= inv;
    }

    float er[NUM_EXPERTS];
    #pragma unroll
    for (int e = 0; e < NUM_EXPERTS; ++e) er[e] = emb[(size_t)r * NUM_EXPERTS + e];
    float f[16];
    #pragma unroll
    for (int j = 0; j < 16; ++j) {
        float s = 0.f;
        #pragma unroll
        for (int e = 0; e < NUM_EXPERTS; ++e) s += v[e][j] * er[e];
        f[j] = fmaxf(s, 0.f);
    }
    unsigned u[8];
    #pragma unroll
    for (int j = 0; j < 8; ++j)
        u[j] = (unsigned)f2b(f[2 * j]) | ((unsigned)f2b(f[2 * j + 1]) << 16);
    int p = pos[r];
    uint4* dst = reinterpret_cast<uint4*>(featsB + (size_t)p * WIDTH + l * 16);
    dst[0] = make_uint4(u[0], u[1], u[2], u[3]);
    dst[1] = make_uint4(u[4], u[5], u[6], u[7]);
}

// ---------------------------------------------------------------------------
// Per-task head MFMA GEMM (16x16x32, r8-verified, unchanged)
// ---------------------------------------------------------------------------
__global__ __launch_bounds__(256) void head_mfma(
    const ushort_t* __restrict__ featsB,
    const int* __restrict__ row_map,
    const int* __restrict__ tstart,
    const int* __restrict__ tcnt,
    const ushort_t* __restrict__ Wht,     // [50][256][1024] bf16
    const float* __restrict__ b_head,
    float* __restrict__ out)
{
    const int task = blockIdx.y;
    const int mt   = blockIdx.x;
    const int cnt  = tcnt[task];
    if (mt * 32 >= cnt) return;
    const int ts = tstart[task];
    const int t = threadIdx.x;
    const int l = t & 63;
    const int w = t >> 6;

    __shared__ __align__(16) ushort_t As[32 * 64];    // 4 KB
    __shared__ __align__(16) ushort_t Bs[256 * 64];   // 32 KB

    const int sr = t >> 3;
    const int sk = ((t & 7) ^ (sr & 7)) * 8;

    const int lm = l & 15;
    const int lq = l >> 4;
    const int ss = lm & 7;

    int arow = ts + mt * 32 + sr;
    if (arow > BATCH - 1) arow = BATCH - 1;
    const ushort_t* __restrict__ Asrc = featsB + (size_t)arow * WIDTH;
    const ushort_t* __restrict__ Bsrc = Wht + (size_t)task * HEAD_DIM * WIDTH;

    f32x4 acc[2][4];
    #pragma unroll
    for (int i = 0; i < 2; ++i)
        #pragma unroll
        for (int j = 0; j < 4; ++j) acc[i][j] = {0.f, 0.f, 0.f, 0.f};

    for (int kt = 0; kt < WIDTH; kt += 64) {
        __syncthreads();
        async16(Asrc + kt + sk, &As[t * 8]);
        #pragma unroll
        for (int p = 0; p < 8; ++p) {
            int n = p * 32 + sr;
            async16(Bsrc + (size_t)n * WIDTH + kt + sk, &Bs[p * 2048 + t * 8]);
        }
        __syncthreads();

        #pragma unroll
        for (int ks = 0; ks < 2; ++ks) {
            const int slot = ((ks * 4 + lq) ^ ss) * 8;
            bf16x8 af[2], bfr[4];
            #pragma unroll
            for (int mi = 0; mi < 2; ++mi)
                af[mi] = *reinterpret_cast<const bf16x8*>(&As[(mi * 16 + lm) * 64 + slot]);
            #pragma unroll
            for (int ni = 0; ni < 4; ++ni)
                bfr[ni] = *reinterpret_cast<const bf16x8*>(&Bs[(w * 64 + ni * 16 + lm) * 64 + slot]);
            #pragma unroll
            for (int mi = 0; mi < 2; ++mi)
                #pragma unroll
                for (int ni = 0; ni < 4; ++ni)
                    acc[mi][ni] = __builtin_amdgcn_mfma_f32_16x16x32_bf16(
                        af[mi], bfr[ni], acc[mi][ni], 0, 0, 0);
        }
    }

    const int rbase = lq * 4;
    #pragma unroll
    for (int ni = 0; ni < 4; ++ni) {
        int d = w * 64 + ni * 16 + lm;
        float bhv = b_head[task * HEAD_DIM + d];
        #pragma unroll
        for (int mi = 0; mi < 2; ++mi) {
            #pragma unroll
            for (int r = 0; r < 4; ++r) {
                int mrow = mt * 32 + mi * 16 + rbase + r;
                if (mrow < cnt) {
                    int b = row_map[ts + mrow];
                    out[(size_t)b * HEAD_DIM + d] = acc[mi][ni][r] + bhv;
                }
            }
        }
    }
}

// ---------------------------------------------------------------------------
extern "C" void kernel_launch(void* const* d_in, const int* in_sizes, int n_in,
                              void* d_out, int out_size, void* d_ws, size_t ws_size,
                              hipStream_t stream) {
    const float* x      = (const float*)d_in[0];
    const float* W_emb  = (const float*)d_in[1];
    const float* b_emb  = (const float*)d_in[2];
    const float* W0     = (const float*)d_in[3];
    const float* b0     = (const float*)d_in[4];
    const float* W1     = (const float*)d_in[5];
    const float* b1     = (const float*)d_in[6];
    const float* Wout   = (const float*)d_in[7];
    const float* bout   = (const float*)d_in[8];
    const float* W_head = (const float*)d_in[9];
    const float* b_head = (const float*)d_in[10];
    float* out = (float*)d_out;

    char* ws = (char*)d_ws;
    size_t off = 0;
    auto take = [&](size_t bytes) { char* p = ws + off; off += (bytes + 255) & ~(size_t)255; return p; };
    float*    emb     = (float*)   take((size_t)BATCH * NUM_EXPERTS * sizeof(float));
    int*      tids    = (int*)     take((size_t)BATCH * sizeof(int));
    int*      pos     = (int*)     take((size_t)BATCH * sizeof(int));
    int*      row_map = (int*)     take((size_t)BATCH * sizeof(int));
    int*      tstart  = (int*)     take((size_t)NUM_TASKS * sizeof(int));
    int*      tcnt    = (int*)     take((size_t)NUM_TASKS * sizeof(int));
    ushort_t* xb      = (ushort_t*)take((size_t)BATCH * FEAT * 2);
    ushort_t* W0t     = (ushort_t*)take((size_t)NUM_EXPERTS * WIDTH * FEAT * 2);
    ushort_t* W1t     = (ushort_t*)take((size_t)NUM_EXPERTS * WIDTH * WIDTH * 2);
    ushort_t* Woutt   = (ushort_t*)take((size_t)NUM_EXPERTS * WIDTH * WIDTH * 2);
    ushort_t* Wht     = (ushort_t*)take((size_t)NUM_TASKS * HEAD_DIM * WIDTH * 2);
    ushort_t* featsB  = (ushort_t*)take((size_t)BATCH * WIDTH * 2);
    char* bufbase = ws + off;

    const size_t ROWB = (size_t)NUM_EXPERTS * WIDTH * 2;  // 16 KB/row
    size_t avail = ws_size > off ? ws_size - off : 0;
    int CHUNK;
    if      (avail >= 2 * (size_t)4096 * ROWB) CHUNK = 4096;
    else if (avail >= 2 * (size_t)2048 * ROWB) CHUNK = 2048;
    else if (avail >= 2 * (size_t)1024 * ROWB) CHUNK = 1024;
    else                                       CHUNK = 512;

    ushort_t* bufA = (ushort_t*)bufbase;
    ushort_t* bufB = (ushort_t*)(bufbase + (size_t)CHUNK * ROWB);

    prepx_kernel<<<BATCH, 64, 0, stream>>>(x, W_emb, b_emb, emb, tids, xb);
    sort_kernel<<<1, 256, 0, stream>>>(tids, pos, row_map, tstart, tcnt);
    conv_t64<<<dim3(FEAT / 64, WIDTH / 64, NUM_EXPERTS), 256, 0, stream>>>(W0, W0t, FEAT, WIDTH);
    conv_t64<<<dim3(WIDTH / 64, WIDTH / 64, NUM_EXPERTS), 256, 0, stream>>>(W1, W1t, WIDTH, WIDTH);
    conv_t64<<<dim3(WIDTH / 64, WIDTH / 64, NUM_EXPERTS), 256, 0, stream>>>(Wout, Woutt, WIDTH, WIDTH);
    conv_t64<<<dim3(WIDTH / 64, HEAD_DIM / 64, NUM_TASKS), 256, 0, stream>>>(W_head, Wht, WIDTH, HEAD_DIM);

    dim3 grid(CHUNK / 128, WIDTH / 256, NUM_EXPERTS);
    for (int r0 = 0; r0 < BATCH; r0 += CHUNK) {
        const ushort_t* xc = xb + (size_t)r0 * FEAT;
        mfma_gemm<true ><<<grid, 256, 0, stream>>>(xc, FEAT, 0, W0t, b0, bufA, FEAT);
        mfma_gemm<true ><<<grid, 256, 0, stream>>>(bufA, NUM_EXPERTS * WIDTH, WIDTH, W1t, b1, bufB, WIDTH);
        mfma_gemm<false><<<grid, 256, 0, stream>>>(bufB, NUM_EXPERTS * WIDTH, WIDTH, Woutt, bout, bufA, WIDTH);
        gs_wave_kernel<<<CHUNK / 4, 256, 0, stream>>>(bufA, emb + (size_t)r0 * NUM_EXPERTS,
                                                      pos + r0, featsB);
    }
    head_mfma<<<dim3(6, NUM_TASKS), 256, 0, stream>>>(featsB, row_map, tstart, tcnt,
                                                      Wht, b_head, out);
}

// Round 12
// 453.255 us; speedup vs baseline: 1.1786x; 1.1786x over previous
//
#include <hip/hip_runtime.h>
#include <hip/hip_bf16.h>

#define NUM_TASKS 50
#define NUM_EXPERTS 8
#define WIDTH 1024
#define FEAT 512
#define HEAD_DIM 256
#define BATCH 4096
#define XCOLS (FEAT + NUM_TASKS)   // 562

typedef unsigned short ushort_t;
typedef short bf16x8 __attribute__((ext_vector_type(8)));
typedef float f32x4 __attribute__((ext_vector_type(4)));
typedef float f32x16 __attribute__((ext_vector_type(16)));

// fp32 -> bf16 (RNE) raw bits
__device__ __forceinline__ ushort_t f2b(float f) {
    unsigned u = __float_as_uint(f);
    unsigned r = (u + 0x7fffu + ((u >> 16) & 1u)) >> 16;
    return (ushort_t)r;
}
__device__ __forceinline__ float b2f_lo(unsigned u) { return __uint_as_float(u << 16); }
__device__ __forceinline__ float b2f_hi(unsigned u) { return __uint_as_float(u & 0xffff0000u); }

__device__ __forceinline__ void async16(const ushort_t* g, ushort_t* l) {
    __builtin_amdgcn_global_load_lds(
        (const __attribute__((address_space(1))) unsigned int*)g,
        (__attribute__((address_space(3))) unsigned int*)l,
        16, 0, 0);
}

// bank-conflict-free swizzle key (r9/r10-verified: 0 conflicts)
__device__ __forceinline__ int swz(int r) { return (r & 7) ^ ((r >> 3) & 3); }

// ---------------------------------------------------------------------------
// prepx: task id + emb + x-feat bf16 conversion (merged)
// ---------------------------------------------------------------------------
__global__ void prepx_kernel(const float* __restrict__ x,
                             const float* __restrict__ W_emb,
                             const float* __restrict__ b_emb,
                             float* __restrict__ emb,
                             int* __restrict__ tids,
                             ushort_t* __restrict__ xb) {
    int b = blockIdx.x;
    int lane = threadIdx.x;  // 64
    const float* xr = x + (size_t)b * XCOLS;
    float v = 0.f;
    if (lane < NUM_TASKS) v = xr[FEAT + lane];
    unsigned long long mask = __ballot(v > 0.5f);
    int tid = __ffsll(mask) - 1;
    if (tid < 0) tid = 0;
    if (tid > NUM_TASKS - 1) tid = NUM_TASKS - 1;
    if (lane == 0) tids[b] = tid;
    if (lane < NUM_EXPERTS)
        emb[(size_t)b * NUM_EXPERTS + lane] =
            W_emb[tid * NUM_EXPERTS + lane] + b_emb[lane];
    float f[8];
    #pragma unroll
    for (int j = 0; j < 8; ++j) f[j] = xr[lane * 8 + j];
    unsigned u[4];
    #pragma unroll
    for (int j = 0; j < 4; ++j)
        u[j] = (unsigned)f2b(f[2 * j]) | ((unsigned)f2b(f[2 * j + 1]) << 16);
    *reinterpret_cast<uint4*>(xb + (size_t)b * FEAT + lane * 8) =
        make_uint4(u[0], u[1], u[2], u[3]);
}

// ---------------------------------------------------------------------------
// counting sort by task
// ---------------------------------------------------------------------------
__global__ void sort_kernel(const int* __restrict__ tids,
                            int* __restrict__ pos,
                            int* __restrict__ row_map,
                            int* __restrict__ tstart,
                            int* __restrict__ tcnt) {
    __shared__ int cnt[NUM_TASKS];
    __shared__ int start[NUM_TASKS];
    __shared__ int rank[NUM_TASKS];
    int t = threadIdx.x;
    if (t < NUM_TASKS) { cnt[t] = 0; rank[t] = 0; }
    __syncthreads();
    for (int b = t; b < BATCH; b += 256) atomicAdd(&cnt[tids[b]], 1);
    __syncthreads();
    if (t == 0) {
        int acc = 0;
        for (int k = 0; k < NUM_TASKS; ++k) { start[k] = acc; acc += cnt[k]; }
    }
    __syncthreads();
    if (t < NUM_TASKS) { tstart[t] = start[t]; tcnt[t] = cnt[t]; }
    for (int b = t; b < BATCH; b += 256) {
        int tk = tids[b];
        int p = start[tk] + atomicAdd(&rank[tk], 1);
        pos[b] = p;
        row_map[p] = b;
    }
}

// ---------------------------------------------------------------------------
// Merged transpose+convert for ALL weights in ONE dispatch.
// Segments (64x64 tiles, fp32 [z][R][C] -> bf16 [z][C][R]):
//   seg0 W0    : z=8,  R=512,  C=1024 -> 1024 tiles
//   seg1 W1    : z=8,  R=1024, C=1024 -> 2048 tiles
//   seg2 Wout  : z=8,  R=1024, C=1024 -> 2048 tiles
//   seg3 W_head: z=50, R=1024, C=256  -> 3200 tiles
// total grid.x = 8320
// ---------------------------------------------------------------------------
#define CONV_NT0 1024
#define CONV_NT1 (CONV_NT0 + 2048)
#define CONV_NT2 (CONV_NT1 + 2048)
#define CONV_NT3 (CONV_NT2 + 3200)

__global__ __launch_bounds__(256) void conv_all(
    const float* __restrict__ W0, const float* __restrict__ W1,
    const float* __restrict__ Wout, const float* __restrict__ W_head,
    ushort_t* __restrict__ W0t, ushort_t* __restrict__ W1t,
    ushort_t* __restrict__ Woutt, ushort_t* __restrict__ Wht) {
    int g = blockIdx.x;
    const float* src; ushort_t* dst; int R, C, rem;
    if (g < CONV_NT0)      { src = W0;     dst = W0t;   R = 512;  C = 1024; rem = g; }
    else if (g < CONV_NT1) { src = W1;     dst = W1t;   R = 1024; C = 1024; rem = g - CONV_NT0; }
    else if (g < CONV_NT2) { src = Wout;   dst = Woutt; R = 1024; C = 1024; rem = g - CONV_NT1; }
    else                   { src = W_head; dst = Wht;   R = 1024; C = 256;  rem = g - CONV_NT2; }
    const int rt = R >> 6, ct = C >> 6;
    const int z  = rem / (rt * ct);
    const int zr = rem - z * (rt * ct);
    const int r0 = (zr / ct) * 64;
    const int c0 = (zr - (zr / ct) * ct) * 64;

    __shared__ float tile[64][65];
    const float* S = src + (size_t)z * R * C;
    ushort_t* D = dst + (size_t)z * R * C;
    int t = threadIdx.x;
    const int ci4 = t & 15, ri = t >> 4;
    #pragma unroll
    for (int p = 0; p < 4; ++p) {
        int r = ri + 16 * p;
        float4 v = *reinterpret_cast<const float4*>(S + (size_t)(r0 + r) * C + c0 + ci4 * 4);
        tile[r][ci4 * 4 + 0] = v.x;
        tile[r][ci4 * 4 + 1] = v.y;
        tile[r][ci4 * 4 + 2] = v.z;
        tile[r][ci4 * 4 + 3] = v.w;
    }
    __syncthreads();
    const int co2 = t & 31, ci = t >> 5;
    #pragma unroll
    for (int p = 0; p < 8; ++p) {
        int c = ci + 8 * p;
        float a = tile[co2 * 2 + 0][c];
        float b = tile[co2 * 2 + 1][c];
        unsigned u = (unsigned)f2b(a) | ((unsigned)f2b(b) << 16);
        *reinterpret_cast<unsigned*>(D + (size_t)(c0 + c) * R + r0 + co2 * 2) = u;
    }
}

// ---------------------------------------------------------------------------
// MFMA expert-batched GEMM, 32x32x16, BM=BN=128, BK=64, dual-safe swizzle.
// EXACT round-10 configuration (best measured: 96.5 us @ K=1024, 0 conflicts).
// r11's 128x256 variant regressed (VGPR 148, 1 block/CU): do not enlarge.
// ---------------------------------------------------------------------------
template <bool RELU>
__global__ __launch_bounds__(256) void mfma_gemm(
    const ushort_t* __restrict__ A, int lda, int aoff,
    const ushort_t* __restrict__ Bt,
    const float* __restrict__ bias,
    ushort_t* __restrict__ C, int K)
{
    const int m0 = blockIdx.x * 128;
    const int n0 = blockIdx.y * 128;
    const int e  = blockIdx.z;
    const int t  = threadIdx.x;
    const int l  = t & 63;

    __shared__ __align__(16) ushort_t As[128 * 64];  // 16 KB
    __shared__ __align__(16) ushort_t Bs[128 * 64];  // 16 KB

    const ushort_t* __restrict__ Ab = A + (size_t)e * aoff + (size_t)m0 * lda;
    const ushort_t* __restrict__ Bb = Bt + ((size_t)e * WIDTH + n0) * K;

    // staging: thread t -> row (t>>3), slot (t&7); loads granule (t&7)^swz(row)
    const int sr = t >> 3;                          // 0..31
    const int sk = ((t & 7) ^ swz(sr)) * 8;         // global k-element offset

    const int w  = t >> 6;
    const int wm = (w >> 1) * 64;
    const int wn = (w & 1) * 64;
    const int ra = l & 31;                          // fragment row within 32
    const int hi = l >> 5;                          // k-half (0/1)
    const int kx = swz(ra);                         // read-side key

    f32x16 acc[2][2];
    #pragma unroll
    for (int i = 0; i < 2; ++i)
        #pragma unroll
        for (int j = 0; j < 2; ++j)
            #pragma unroll
            for (int q = 0; q < 16; ++q) acc[i][j][q] = 0.f;

    for (int kt = 0; kt < K; kt += 64) {
        __syncthreads();
        #pragma unroll
        for (int p = 0; p < 4; ++p) {
            async16(Ab + (size_t)(p * 32 + sr) * lda + kt + sk, &As[p * 2048 + t * 8]);
            async16(Bb + (size_t)(p * 32 + sr) * K   + kt + sk, &Bs[p * 2048 + t * 8]);
        }
        __syncthreads();

        #pragma unroll
        for (int ks = 0; ks < 4; ++ks) {
            const int slot = ((ks * 2 + hi) ^ kx) * 8;
            bf16x8 af[2], bfr[2];
            #pragma unroll
            for (int mi = 0; mi < 2; ++mi)
                af[mi] = *reinterpret_cast<const bf16x8*>(&As[(wm + mi * 32 + ra) * 64 + slot]);
            #pragma unroll
            for (int ni = 0; ni < 2; ++ni)
                bfr[ni] = *reinterpret_cast<const bf16x8*>(&Bs[(wn + ni * 32 + ra) * 64 + slot]);
            #pragma unroll
            for (int mi = 0; mi < 2; ++mi)
                #pragma unroll
                for (int ni = 0; ni < 2; ++ni)
                    acc[mi][ni] = __builtin_amdgcn_mfma_f32_32x32x16_bf16(
                        af[mi], bfr[ni], acc[mi][ni], 0, 0, 0);
        }
    }

    const int lrow = 4 * hi;
    #pragma unroll
    for (int mi = 0; mi < 2; ++mi) {
        #pragma unroll
        for (int ni = 0; ni < 2; ++ni) {
            int col = n0 + wn + ni * 32 + ra;
            float bv = bias[e * WIDTH + col];
            #pragma unroll
            for (int r = 0; r < 16; ++r) {
                int row = m0 + wm + mi * 32 + 8 * (r >> 2) + lrow + (r & 3);
                float v = acc[mi][ni][r] + bv;
                if (RELU) v = fmaxf(v, 0.f);
                C[(size_t)row * (NUM_EXPERTS * WIDTH) + e * WIDTH + col] = f2b(v);
            }
        }
    }
}

// ---------------------------------------------------------------------------
// Wave-per-row register Gram-Schmidt -> bf16 feats at task-sorted slot
// ---------------------------------------------------------------------------
__device__ __forceinline__ float wave_sum(float x) {
    #pragma unroll
    for (int off = 1; off < 64; off <<= 1) x += __shfl_xor(x, off, 64);
    return x;
}
__device__ __forceinline__ void u2f8(uint4 a, float* f) {
    f[0] = b2f_lo(a.x); f[1] = b2f_hi(a.x);
    f[2] = b2f_lo(a.y); f[3] = b2f_hi(a.y);
    f[4] = b2f_lo(a.z); f[5] = b2f_hi(a.z);
    f[6] = b2f_lo(a.w); f[7] = b2f_hi(a.w);
}

__global__ __launch_bounds__(256, 1) void gs_wave_kernel(
    const ushort_t* __restrict__ eo,   // [CHUNK][8][1024] bf16
    const float* __restrict__ emb,     // [CHUNK][8]
    const int* __restrict__ pos,       // [CHUNK] global sorted slot
    ushort_t* __restrict__ featsB)     // [BATCH][1024] bf16 (sorted)
{
    const int w = threadIdx.x >> 6;
    const int l = threadIdx.x & 63;
    const int r = blockIdx.x * 4 + w;

    float v[NUM_EXPERTS][16];
    const ushort_t* row = eo + (size_t)r * (NUM_EXPERTS * WIDTH);
    #pragma unroll
    for (int e = 0; e < NUM_EXPERTS; ++e) {
        const uint4* p = reinterpret_cast<const uint4*>(row + e * WIDTH + l * 16);
        u2f8(p[0], &v[e][0]);
        u2f8(p[1], &v[e][8]);
    }

    {
        float s = 0.f;
        #pragma unroll
        for (int j = 0; j < 16; ++j) s += v[0][j] * v[0][j];
        s = wave_sum(s);
        float inv = 1.f / sqrtf(s);
        #pragma unroll
        for (int j = 0; j < 16; ++j) v[0][j] *= inv;
    }

    #pragma unroll
    for (int i = 1; i < NUM_EXPERTS; ++i) {
        float c[NUM_EXPERTS];
        #pragma unroll
        for (int jj = 0; jj < i; ++jj) {
            float p = 0.f;
            #pragma unroll
            for (int j = 0; j < 16; ++j) p += v[i][j] * v[jj][j];
            c[jj] = wave_sum(p);
        }
        float s = 0.f;
        #pragma unroll
        for (int j = 0; j < 16; ++j) {
            float wv = v[i][j];
            #pragma unroll
            for (int jj = 0; jj < i; ++jj) wv -= c[jj] * v[jj][j];
            v[i][j] = wv;
            s += wv * wv;
        }
        s = wave_sum(s);
        float inv = 1.f / sqrtf(s);
        #pragma unroll
        for (int j = 0; j < 16; ++j) v[i][j] *= inv;
    }

    float er[NUM_EXPERTS];
    #pragma unroll
    for (int e = 0; e < NUM_EXPERTS; ++e) er[e] = emb[(size_t)r * NUM_EXPERTS + e];
    float f[16];
    #pragma unroll
    for (int j = 0; j < 16; ++j) {
        float s = 0.f;
        #pragma unroll
        for (int e = 0; e < NUM_EXPERTS; ++e) s += v[e][j] * er[e];
        f[j] = fmaxf(s, 0.f);
    }
    unsigned u[8];
    #pragma unroll
    for (int j = 0; j < 8; ++j)
        u[j] = (unsigned)f2b(f[2 * j]) | ((unsigned)f2b(f[2 * j + 1]) << 16);
    int p = pos[r];
    uint4* dst = reinterpret_cast<uint4*>(featsB + (size_t)p * WIDTH + l * 16);
    dst[0] = make_uint4(u[0], u[1], u[2], u[3]);
    dst[1] = make_uint4(u[4], u[5], u[6], u[7]);
}

// ---------------------------------------------------------------------------
// Per-task head MFMA GEMM (16x16x32, r8-verified, unchanged)
// ---------------------------------------------------------------------------
__global__ __launch_bounds__(256) void head_mfma(
    const ushort_t* __restrict__ featsB,
    const int* __restrict__ row_map,
    const int* __restrict__ tstart,
    const int* __restrict__ tcnt,
    const ushort_t* __restrict__ Wht,     // [50][256][1024] bf16
    const float* __restrict__ b_head,
    float* __restrict__ out)
{
    const int task = blockIdx.y;
    const int mt   = blockIdx.x;
    const int cnt  = tcnt[task];
    if (mt * 32 >= cnt) return;
    const int ts = tstart[task];
    const int t = threadIdx.x;
    const int l = t & 63;
    const int w = t >> 6;

    __shared__ __align__(16) ushort_t As[32 * 64];    // 4 KB
    __shared__ __align__(16) ushort_t Bs[256 * 64];   // 32 KB

    const int sr = t >> 3;
    const int sk = ((t & 7) ^ (sr & 7)) * 8;

    const int lm = l & 15;
    const int lq = l >> 4;
    const int ss = lm & 7;

    int arow = ts + mt * 32 + sr;
    if (arow > BATCH - 1) arow = BATCH - 1;
    const ushort_t* __restrict__ Asrc = featsB + (size_t)arow * WIDTH;
    const ushort_t* __restrict__ Bsrc = Wht + (size_t)task * HEAD_DIM * WIDTH;

    f32x4 acc[2][4];
    #pragma unroll
    for (int i = 0; i < 2; ++i)
        #pragma unroll
        for (int j = 0; j < 4; ++j) acc[i][j] = {0.f, 0.f, 0.f, 0.f};

    for (int kt = 0; kt < WIDTH; kt += 64) {
        __syncthreads();
        async16(Asrc + kt + sk, &As[t * 8]);
        #pragma unroll
        for (int p = 0; p < 8; ++p) {
            int n = p * 32 + sr;
            async16(Bsrc + (size_t)n * WIDTH + kt + sk, &Bs[p * 2048 + t * 8]);
        }
        __syncthreads();

        #pragma unroll
        for (int ks = 0; ks < 2; ++ks) {
            const int slot = ((ks * 4 + lq) ^ ss) * 8;
            bf16x8 af[2], bfr[4];
            #pragma unroll
            for (int mi = 0; mi < 2; ++mi)
                af[mi] = *reinterpret_cast<const bf16x8*>(&As[(mi * 16 + lm) * 64 + slot]);
            #pragma unroll
            for (int ni = 0; ni < 4; ++ni)
                bfr[ni] = *reinterpret_cast<const bf16x8*>(&Bs[(w * 64 + ni * 16 + lm) * 64 + slot]);
            #pragma unroll
            for (int mi = 0; mi < 2; ++mi)
                #pragma unroll
                for (int ni = 0; ni < 4; ++ni)
                    acc[mi][ni] = __builtin_amdgcn_mfma_f32_16x16x32_bf16(
                        af[mi], bfr[ni], acc[mi][ni], 0, 0, 0);
        }
    }

    const int rbase = lq * 4;
    #pragma unroll
    for (int ni = 0; ni < 4; ++ni) {
        int d = w * 64 + ni * 16 + lm;
        float bhv = b_head[task * HEAD_DIM + d];
        #pragma unroll
        for (int mi = 0; mi < 2; ++mi) {
            #pragma unroll
            for (int r = 0; r < 4; ++r) {
                int mrow = mt * 32 + mi * 16 + rbase + r;
                if (mrow < cnt) {
                    int b = row_map[ts + mrow];
                    out[(size_t)b * HEAD_DIM + d] = acc[mi][ni][r] + bhv;
                }
            }
        }
    }
}

// ---------------------------------------------------------------------------
extern "C" void kernel_launch(void* const* d_in, const int* in_sizes, int n_in,
                              void* d_out, int out_size, void* d_ws, size_t ws_size,
                              hipStream_t stream) {
    const float* x      = (const float*)d_in[0];
    const float* W_emb  = (const float*)d_in[1];
    const float* b_emb  = (const float*)d_in[2];
    const float* W0     = (const float*)d_in[3];
    const float* b0     = (const float*)d_in[4];
    const float* W1     = (const float*)d_in[5];
    const float* b1     = (const float*)d_in[6];
    const float* Wout   = (const float*)d_in[7];
    const float* bout   = (const float*)d_in[8];
    const float* W_head = (const float*)d_in[9];
    const float* b_head = (const float*)d_in[10];
    float* out = (float*)d_out;

    char* ws = (char*)d_ws;
    size_t off = 0;
    auto take = [&](size_t bytes) { char* p = ws + off; off += (bytes + 255) & ~(size_t)255; return p; };
    float*    emb     = (float*)   take((size_t)BATCH * NUM_EXPERTS * sizeof(float));
    int*      tids    = (int*)     take((size_t)BATCH * sizeof(int));
    int*      pos     = (int*)     take((size_t)BATCH * sizeof(int));
    int*      row_map = (int*)     take((size_t)BATCH * sizeof(int));
    int*      tstart  = (int*)     take((size_t)NUM_TASKS * sizeof(int));
    int*      tcnt    = (int*)     take((size_t)NUM_TASKS * sizeof(int));
    ushort_t* xb      = (ushort_t*)take((size_t)BATCH * FEAT * 2);
    ushort_t* W0t     = (ushort_t*)take((size_t)NUM_EXPERTS * WIDTH * FEAT * 2);
    ushort_t* W1t     = (ushort_t*)take((size_t)NUM_EXPERTS * WIDTH * WIDTH * 2);
    ushort_t* Woutt   = (ushort_t*)take((size_t)NUM_EXPERTS * WIDTH * WIDTH * 2);
    ushort_t* Wht     = (ushort_t*)take((size_t)NUM_TASKS * HEAD_DIM * WIDTH * 2);
    ushort_t* featsB  = (ushort_t*)take((size_t)BATCH * WIDTH * 2);
    char* bufbase = ws + off;

    const size_t ROWB = (size_t)NUM_EXPERTS * WIDTH * 2;  // 16 KB/row
    size_t avail = ws_size > off ? ws_size - off : 0;
    int CHUNK;
    if      (avail >= 2 * (size_t)4096 * ROWB) CHUNK = 4096;
    else if (avail >= 2 * (size_t)2048 * ROWB) CHUNK = 2048;
    else if (avail >= 2 * (size_t)1024 * ROWB) CHUNK = 1024;
    else                                       CHUNK = 512;

    ushort_t* bufA = (ushort_t*)bufbase;
    ushort_t* bufB = (ushort_t*)(bufbase + (size_t)CHUNK * ROWB);

    prepx_kernel<<<BATCH, 64, 0, stream>>>(x, W_emb, b_emb, emb, tids, xb);
    sort_kernel<<<1, 256, 0, stream>>>(tids, pos, row_map, tstart, tcnt);
    conv_all<<<CONV_NT3, 256, 0, stream>>>(W0, W1, Wout, W_head, W0t, W1t, Woutt, Wht);

    dim3 grid(CHUNK / 128, WIDTH / 128, NUM_EXPERTS);
    for (int r0 = 0; r0 < BATCH; r0 += CHUNK) {
        const ushort_t* xc = xb + (size_t)r0 * FEAT;
        mfma_gemm<true ><<<grid, 256, 0, stream>>>(xc, FEAT, 0, W0t, b0, bufA, FEAT);
        mfma_gemm<true ><<<grid, 256, 0, stream>>>(bufA, NUM_EXPERTS * WIDTH, WIDTH, W1t, b1, bufB, WIDTH);
        mfma_gemm<false><<<grid, 256, 0, stream>>>(bufB, NUM_EXPERTS * WIDTH, WIDTH, Woutt, bout, bufA, WIDTH);
        gs_wave_kernel<<<CHUNK / 4, 256, 0, stream>>>(bufA, emb + (size_t)r0 * NUM_EXPERTS,
                                                      pos + r0, featsB);
    }
    head_mfma<<<dim3(6, NUM_TASKS), 256, 0, stream>>>(featsB, row_map, tstart, tcnt,
                                                      Wht, b_head, out);
}

// Round 13
// 440.637 us; speedup vs baseline: 1.2123x; 1.0286x over previous
//
#include <hip/hip_runtime.h>
#include <hip/hip_bf16.h>

#define NUM_TASKS 50
#define NUM_EXPERTS 8
#define WIDTH 1024
#define FEAT 512
#define HEAD_DIM 256
#define BATCH 4096
#define XCOLS (FEAT + NUM_TASKS)   // 562

typedef unsigned short ushort_t;
typedef short bf16x8 __attribute__((ext_vector_type(8)));
typedef float f32x4 __attribute__((ext_vector_type(4)));
typedef float f32x16 __attribute__((ext_vector_type(16)));

// fp32 -> bf16 (RNE) raw bits
__device__ __forceinline__ ushort_t f2b(float f) {
    unsigned u = __float_as_uint(f);
    unsigned r = (u + 0x7fffu + ((u >> 16) & 1u)) >> 16;
    return (ushort_t)r;
}
__device__ __forceinline__ float b2f_lo(unsigned u) { return __uint_as_float(u << 16); }
__device__ __forceinline__ float b2f_hi(unsigned u) { return __uint_as_float(u & 0xffff0000u); }

__device__ __forceinline__ void async16(const ushort_t* g, ushort_t* l) {
    __builtin_amdgcn_global_load_lds(
        (const __attribute__((address_space(1))) unsigned int*)g,
        (__attribute__((address_space(3))) unsigned int*)l,
        16, 0, 0);
}

// bank-conflict-free swizzle key (r9/r10-verified: 0 conflicts); period 32 in r
__device__ __forceinline__ int swz(int r) { return (r & 7) ^ ((r >> 3) & 3); }

// ---------------------------------------------------------------------------
// prepx: task id + emb + x-feat bf16 conversion (merged)
// ---------------------------------------------------------------------------
__global__ void prepx_kernel(const float* __restrict__ x,
                             const float* __restrict__ W_emb,
                             const float* __restrict__ b_emb,
                             float* __restrict__ emb,
                             int* __restrict__ tids,
                             ushort_t* __restrict__ xb) {
    int b = blockIdx.x;
    int lane = threadIdx.x;  // 64
    const float* xr = x + (size_t)b * XCOLS;
    float v = 0.f;
    if (lane < NUM_TASKS) v = xr[FEAT + lane];
    unsigned long long mask = __ballot(v > 0.5f);
    int tid = __ffsll(mask) - 1;
    if (tid < 0) tid = 0;
    if (tid > NUM_TASKS - 1) tid = NUM_TASKS - 1;
    if (lane == 0) tids[b] = tid;
    if (lane < NUM_EXPERTS)
        emb[(size_t)b * NUM_EXPERTS + lane] =
            W_emb[tid * NUM_EXPERTS + lane] + b_emb[lane];
    float f[8];
    #pragma unroll
    for (int j = 0; j < 8; ++j) f[j] = xr[lane * 8 + j];
    unsigned u[4];
    #pragma unroll
    for (int j = 0; j < 4; ++j)
        u[j] = (unsigned)f2b(f[2 * j]) | ((unsigned)f2b(f[2 * j + 1]) << 16);
    *reinterpret_cast<uint4*>(xb + (size_t)b * FEAT + lane * 8) =
        make_uint4(u[0], u[1], u[2], u[3]);
}

// ---------------------------------------------------------------------------
// counting sort by task
// ---------------------------------------------------------------------------
__global__ void sort_kernel(const int* __restrict__ tids,
                            int* __restrict__ pos,
                            int* __restrict__ row_map,
                            int* __restrict__ tstart,
                            int* __restrict__ tcnt) {
    __shared__ int cnt[NUM_TASKS];
    __shared__ int start[NUM_TASKS];
    __shared__ int rank[NUM_TASKS];
    int t = threadIdx.x;
    if (t < NUM_TASKS) { cnt[t] = 0; rank[t] = 0; }
    __syncthreads();
    for (int b = t; b < BATCH; b += 256) atomicAdd(&cnt[tids[b]], 1);
    __syncthreads();
    if (t == 0) {
        int acc = 0;
        for (int k = 0; k < NUM_TASKS; ++k) { start[k] = acc; acc += cnt[k]; }
    }
    __syncthreads();
    if (t < NUM_TASKS) { tstart[t] = start[t]; tcnt[t] = cnt[t]; }
    for (int b = t; b < BATCH; b += 256) {
        int tk = tids[b];
        int p = start[tk] + atomicAdd(&rank[tk], 1);
        pos[b] = p;
        row_map[p] = b;
    }
}

// ---------------------------------------------------------------------------
// Merged transpose+convert for ALL weights in ONE dispatch (r12-verified)
// ---------------------------------------------------------------------------
#define CONV_NT0 1024
#define CONV_NT1 (CONV_NT0 + 2048)
#define CONV_NT2 (CONV_NT1 + 2048)
#define CONV_NT3 (CONV_NT2 + 3200)

__global__ __launch_bounds__(256) void conv_all(
    const float* __restrict__ W0, const float* __restrict__ W1,
    const float* __restrict__ Wout, const float* __restrict__ W_head,
    ushort_t* __restrict__ W0t, ushort_t* __restrict__ W1t,
    ushort_t* __restrict__ Woutt, ushort_t* __restrict__ Wht) {
    int g = blockIdx.x;
    const float* src; ushort_t* dst; int R, C, rem;
    if (g < CONV_NT0)      { src = W0;     dst = W0t;   R = 512;  C = 1024; rem = g; }
    else if (g < CONV_NT1) { src = W1;     dst = W1t;   R = 1024; C = 1024; rem = g - CONV_NT0; }
    else if (g < CONV_NT2) { src = Wout;   dst = Woutt; R = 1024; C = 1024; rem = g - CONV_NT1; }
    else                   { src = W_head; dst = Wht;   R = 1024; C = 256;  rem = g - CONV_NT2; }
    const int rt = R >> 6, ct = C >> 6;
    const int z  = rem / (rt * ct);
    const int zr = rem - z * (rt * ct);
    const int r0 = (zr / ct) * 64;
    const int c0 = (zr - (zr / ct) * ct) * 64;

    __shared__ float tile[64][65];
    const float* S = src + (size_t)z * R * C;
    ushort_t* D = dst + (size_t)z * R * C;
    int t = threadIdx.x;
    const int ci4 = t & 15, ri = t >> 4;
    #pragma unroll
    for (int p = 0; p < 4; ++p) {
        int r = ri + 16 * p;
        float4 v = *reinterpret_cast<const float4*>(S + (size_t)(r0 + r) * C + c0 + ci4 * 4);
        tile[r][ci4 * 4 + 0] = v.x;
        tile[r][ci4 * 4 + 1] = v.y;
        tile[r][ci4 * 4 + 2] = v.z;
        tile[r][ci4 * 4 + 3] = v.w;
    }
    __syncthreads();
    const int co2 = t & 31, ci = t >> 5;
    #pragma unroll
    for (int p = 0; p < 8; ++p) {
        int c = ci + 8 * p;
        float a = tile[co2 * 2 + 0][c];
        float b = tile[co2 * 2 + 1][c];
        unsigned u = (unsigned)f2b(a) | ((unsigned)f2b(b) << 16);
        *reinterpret_cast<unsigned*>(D + (size_t)(c0 + c) * R + r0 + co2 * 2) = u;
    }
}

// ---------------------------------------------------------------------------
// MFMA expert-batched GEMM, 32x32x16, BM=256 BN=128 BK=64, 512 threads
// (8 waves, per-wave 2x2 of 32x32 -> acc stays 64 VGPR; r11's failure was
// per-WAVE tile growth, not block tile). Staging 48 KB/iter for 2x FLOP of
// the 128^2 tile -> L2 demand 63.5 -> 46.5 B/cyc/CU (under ~60 ceiling).
// Dual-safe swizzle, period 32 -> staging/read keys consistent for 64-row
// passes. Per-element k-order unchanged vs r10/r12 (bitwise-same C).
// ---------------------------------------------------------------------------
template <bool RELU>
__global__ __launch_bounds__(512) void mfma_gemm(
    const ushort_t* __restrict__ A, int lda, int aoff,
    const ushort_t* __restrict__ Bt,
    const float* __restrict__ bias,
    ushort_t* __restrict__ C, int K)
{
    const int m0 = blockIdx.x * 256;
    const int n0 = blockIdx.y * 128;
    const int e  = blockIdx.z;
    const int t  = threadIdx.x;
    const int l  = t & 63;

    __shared__ __align__(16) ushort_t As[256 * 64];  // 32 KB
    __shared__ __align__(16) ushort_t Bs[128 * 64];  // 16 KB

    const ushort_t* __restrict__ Ab = A + (size_t)e * aoff + (size_t)m0 * lda;
    const ushort_t* __restrict__ Bb = Bt + ((size_t)e * WIDTH + n0) * K;

    // staging: thread t -> row (t>>3) within a 64-row pass, slot (t&7);
    // loads global k-granule (t&7)^swz(row)
    const int sr = t >> 3;                          // 0..63
    const int sk = ((t & 7) ^ swz(sr)) * 8;         // global k-element offset

    const int w  = t >> 6;                          // 0..7
    const int wm = (w & 3) * 64;                    // 4 m-slabs
    const int wn = (w >> 2) * 64;                   // 2 n-slabs
    const int ra = l & 31;                          // fragment row within 32
    const int hi = l >> 5;                          // k-half (0/1)
    const int kx = swz(ra);                         // read-side key

    f32x16 acc[2][2];
    #pragma unroll
    for (int i = 0; i < 2; ++i)
        #pragma unroll
        for (int j = 0; j < 2; ++j)
            #pragma unroll
            for (int q = 0; q < 16; ++q) acc[i][j][q] = 0.f;

    for (int kt = 0; kt < K; kt += 64) {
        __syncthreads();
        #pragma unroll
        for (int p = 0; p < 4; ++p)   // A: 4 passes x 64 rows
            async16(Ab + (size_t)(p * 64 + sr) * lda + kt + sk, &As[p * 4096 + t * 8]);
        #pragma unroll
        for (int p = 0; p < 2; ++p)   // B: 2 passes x 64 rows
            async16(Bb + (size_t)(p * 64 + sr) * K   + kt + sk, &Bs[p * 4096 + t * 8]);
        __syncthreads();

        #pragma unroll
        for (int ks = 0; ks < 4; ++ks) {
            const int slot = ((ks * 2 + hi) ^ kx) * 8;
            bf16x8 af[2], bfr[2];
            #pragma unroll
            for (int mi = 0; mi < 2; ++mi)
                af[mi] = *reinterpret_cast<const bf16x8*>(&As[(wm + mi * 32 + ra) * 64 + slot]);
            #pragma unroll
            for (int ni = 0; ni < 2; ++ni)
                bfr[ni] = *reinterpret_cast<const bf16x8*>(&Bs[(wn + ni * 32 + ra) * 64 + slot]);
            #pragma unroll
            for (int mi = 0; mi < 2; ++mi)
                #pragma unroll
                for (int ni = 0; ni < 2; ++ni)
                    acc[mi][ni] = __builtin_amdgcn_mfma_f32_32x32x16_bf16(
                        af[mi], bfr[ni], acc[mi][ni], 0, 0, 0);
        }
    }

    const int lrow = 4 * hi;
    #pragma unroll
    for (int mi = 0; mi < 2; ++mi) {
        #pragma unroll
        for (int ni = 0; ni < 2; ++ni) {
            int col = n0 + wn + ni * 32 + ra;
            float bv = bias[e * WIDTH + col];
            #pragma unroll
            for (int r = 0; r < 16; ++r) {
                int row = m0 + wm + mi * 32 + 8 * (r >> 2) + lrow + (r & 3);
                float v = acc[mi][ni][r] + bv;
                if (RELU) v = fmaxf(v, 0.f);
                C[(size_t)row * (NUM_EXPERTS * WIDTH) + e * WIDTH + col] = f2b(v);
            }
        }
    }
}

// ---------------------------------------------------------------------------
// Wave-per-row register Gram-Schmidt -> bf16 feats at task-sorted slot
// ---------------------------------------------------------------------------
__device__ __forceinline__ float wave_sum(float x) {
    #pragma unroll
    for (int off = 1; off < 64; off <<= 1) x += __shfl_xor(x, off, 64);
    return x;
}
__device__ __forceinline__ void u2f8(uint4 a, float* f) {
    f[0] = b2f_lo(a.x); f[1] = b2f_hi(a.x);
    f[2] = b2f_lo(a.y); f[3] = b2f_hi(a.y);
    f[4] = b2f_lo(a.z); f[5] = b2f_hi(a.z);
    f[6] = b2f_lo(a.w); f[7] = b2f_hi(a.w);
}

__global__ __launch_bounds__(256, 1) void gs_wave_kernel(
    const ushort_t* __restrict__ eo,   // [CHUNK][8][1024] bf16
    const float* __restrict__ emb,     // [CHUNK][8]
    const int* __restrict__ pos,       // [CHUNK] global sorted slot
    ushort_t* __restrict__ featsB)     // [BATCH][1024] bf16 (sorted)
{
    const int w = threadIdx.x >> 6;
    const int l = threadIdx.x & 63;
    const int r = blockIdx.x * 4 + w;

    float v[NUM_EXPERTS][16];
    const ushort_t* row = eo + (size_t)r * (NUM_EXPERTS * WIDTH);
    #pragma unroll
    for (int e = 0; e < NUM_EXPERTS; ++e) {
        const uint4* p = reinterpret_cast<const uint4*>(row + e * WIDTH + l * 16);
        u2f8(p[0], &v[e][0]);
        u2f8(p[1], &v[e][8]);
    }

    {
        float s = 0.f;
        #pragma unroll
        for (int j = 0; j < 16; ++j) s += v[0][j] * v[0][j];
        s = wave_sum(s);
        float inv = 1.f / sqrtf(s);
        #pragma unroll
        for (int j = 0; j < 16; ++j) v[0][j] *= inv;
    }

    #pragma unroll
    for (int i = 1; i < NUM_EXPERTS; ++i) {
        float c[NUM_EXPERTS];
        #pragma unroll
        for (int jj = 0; jj < i; ++jj) {
            float p = 0.f;
            #pragma unroll
            for (int j = 0; j < 16; ++j) p += v[i][j] * v[jj][j];
            c[jj] = wave_sum(p);
        }
        float s = 0.f;
        #pragma unroll
        for (int j = 0; j < 16; ++j) {
            float wv = v[i][j];
            #pragma unroll
            for (int jj = 0; jj < i; ++jj) wv -= c[jj] * v[jj][j];
            v[i][j] = wv;
            s += wv * wv;
        }
        s = wave_sum(s);
        float inv = 1.f / sqrtf(s);
        #pragma unroll
        for (int j = 0; j < 16; ++j) v[i][j] *= inv;
    }

    float er[NUM_EXPERTS];
    #pragma unroll
    for (int e = 0; e < NUM_EXPERTS; ++e) er[e] = emb[(size_t)r * NUM_EXPERTS + e];
    float f[16];
    #pragma unroll
    for (int j = 0; j < 16; ++j) {
        float s = 0.f;
        #pragma unroll
        for (int e = 0; e < NUM_EXPERTS; ++e) s += v[e][j] * er[e];
        f[j] = fmaxf(s, 0.f);
    }
    unsigned u[8];
    #pragma unroll
    for (int j = 0; j < 8; ++j)
        u[j] = (unsigned)f2b(f[2 * j]) | ((unsigned)f2b(f[2 * j + 1]) << 16);
    int p = pos[r];
    uint4* dst = reinterpret_cast<uint4*>(featsB + (size_t)p * WIDTH + l * 16);
    dst[0] = make_uint4(u[0], u[1], u[2], u[3]);
    dst[1] = make_uint4(u[4], u[5], u[6], u[7]);
}

// ---------------------------------------------------------------------------
// Per-task head MFMA GEMM (16x16x32, r8-verified, unchanged)
// ---------------------------------------------------------------------------
__global__ __launch_bounds__(256) void head_mfma(
    const ushort_t* __restrict__ featsB,
    const int* __restrict__ row_map,
    const int* __restrict__ tstart,
    const int* __restrict__ tcnt,
    const ushort_t* __restrict__ Wht,     // [50][256][1024] bf16
    const float* __restrict__ b_head,
    float* __restrict__ out)
{
    const int task = blockIdx.y;
    const int mt   = blockIdx.x;
    const int cnt  = tcnt[task];
    if (mt * 32 >= cnt) return;
    const int ts = tstart[task];
    const int t = threadIdx.x;
    const int l = t & 63;
    const int w = t >> 6;

    __shared__ __align__(16) ushort_t As[32 * 64];    // 4 KB
    __shared__ __align__(16) ushort_t Bs[256 * 64];   // 32 KB

    const int sr = t >> 3;
    const int sk = ((t & 7) ^ (sr & 7)) * 8;

    const int lm = l & 15;
    const int lq = l >> 4;
    const int ss = lm & 7;

    int arow = ts + mt * 32 + sr;
    if (arow > BATCH - 1) arow = BATCH - 1;
    const ushort_t* __restrict__ Asrc = featsB + (size_t)arow * WIDTH;
    const ushort_t* __restrict__ Bsrc = Wht + (size_t)task * HEAD_DIM * WIDTH;

    f32x4 acc[2][4];
    #pragma unroll
    for (int i = 0; i < 2; ++i)
        #pragma unroll
        for (int j = 0; j < 4; ++j) acc[i][j] = {0.f, 0.f, 0.f, 0.f};

    for (int kt = 0; kt < WIDTH; kt += 64) {
        __syncthreads();
        async16(Asrc + kt + sk, &As[t * 8]);
        #pragma unroll
        for (int p = 0; p < 8; ++p) {
            int n = p * 32 + sr;
            async16(Bsrc + (size_t)n * WIDTH + kt + sk, &Bs[p * 2048 + t * 8]);
        }
        __syncthreads();

        #pragma unroll
        for (int ks = 0; ks < 2; ++ks) {
            const int slot = ((ks * 4 + lq) ^ ss) * 8;
            bf16x8 af[2], bfr[4];
            #pragma unroll
            for (int mi = 0; mi < 2; ++mi)
                af[mi] = *reinterpret_cast<const bf16x8*>(&As[(mi * 16 + lm) * 64 + slot]);
            #pragma unroll
            for (int ni = 0; ni < 4; ++ni)
                bfr[ni] = *reinterpret_cast<const bf16x8*>(&Bs[(w * 64 + ni * 16 + lm) * 64 + slot]);
            #pragma unroll
            for (int mi = 0; mi < 2; ++mi)
                #pragma unroll
                for (int ni = 0; ni < 4; ++ni)
                    acc[mi][ni] = __builtin_amdgcn_mfma_f32_16x16x32_bf16(
                        af[mi], bfr[ni], acc[mi][ni], 0, 0, 0);
        }
    }

    const int rbase = lq * 4;
    #pragma unroll
    for (int ni = 0; ni < 4; ++ni) {
        int d = w * 64 + ni * 16 + lm;
        float bhv = b_head[task * HEAD_DIM + d];
        #pragma unroll
        for (int mi = 0; mi < 2; ++mi) {
            #pragma unroll
            for (int r = 0; r < 4; ++r) {
                int mrow = mt * 32 + mi * 16 + rbase + r;
                if (mrow < cnt) {
                    int b = row_map[ts + mrow];
                    out[(size_t)b * HEAD_DIM + d] = acc[mi][ni][r] + bhv;
                }
            }
        }
    }
}

// ---------------------------------------------------------------------------
extern "C" void kernel_launch(void* const* d_in, const int* in_sizes, int n_in,
                              void* d_out, int out_size, void* d_ws, size_t ws_size,
                              hipStream_t stream) {
    const float* x      = (const float*)d_in[0];
    const float* W_emb  = (const float*)d_in[1];
    const float* b_emb  = (const float*)d_in[2];
    const float* W0     = (const float*)d_in[3];
    const float* b0     = (const float*)d_in[4];
    const float* W1     = (const float*)d_in[5];
    const float* b1     = (const float*)d_in[6];
    const float* Wout   = (const float*)d_in[7];
    const float* bout   = (const float*)d_in[8];
    const float* W_head = (const float*)d_in[9];
    const float* b_head = (const float*)d_in[10];
    float* out = (float*)d_out;

    char* ws = (char*)d_ws;
    size_t off = 0;
    auto take = [&](size_t bytes) { char* p = ws + off; off += (bytes + 255) & ~(size_t)255; return p; };
    float*    emb     = (float*)   take((size_t)BATCH * NUM_EXPERTS * sizeof(float));
    int*      tids    = (int*)     take((size_t)BATCH * sizeof(int));
    int*      pos     = (int*)     take((size_t)BATCH * sizeof(int));
    int*      row_map = (int*)     take((size_t)BATCH * sizeof(int));
    int*      tstart  = (int*)     take((size_t)NUM_TASKS * sizeof(int));
    int*      tcnt    = (int*)     take((size_t)NUM_TASKS * sizeof(int));
    ushort_t* xb      = (ushort_t*)take((size_t)BATCH * FEAT * 2);
    ushort_t* W0t     = (ushort_t*)take((size_t)NUM_EXPERTS * WIDTH * FEAT * 2);
    ushort_t* W1t     = (ushort_t*)take((size_t)NUM_EXPERTS * WIDTH * WIDTH * 2);
    ushort_t* Woutt   = (ushort_t*)take((size_t)NUM_EXPERTS * WIDTH * WIDTH * 2);
    ushort_t* Wht     = (ushort_t*)take((size_t)NUM_TASKS * HEAD_DIM * WIDTH * 2);
    ushort_t* featsB  = (ushort_t*)take((size_t)BATCH * WIDTH * 2);
    char* bufbase = ws + off;

    const size_t ROWB = (size_t)NUM_EXPERTS * WIDTH * 2;  // 16 KB/row
    size_t avail = ws_size > off ? ws_size - off : 0;
    int CHUNK;
    if      (avail >= 2 * (size_t)4096 * ROWB) CHUNK = 4096;
    else if (avail >= 2 * (size_t)2048 * ROWB) CHUNK = 2048;
    else if (avail >= 2 * (size_t)1024 * ROWB) CHUNK = 1024;
    else                                       CHUNK = 512;

    ushort_t* bufA = (ushort_t*)bufbase;
    ushort_t* bufB = (ushort_t*)(bufbase + (size_t)CHUNK * ROWB);

    prepx_kernel<<<BATCH, 64, 0, stream>>>(x, W_emb, b_emb, emb, tids, xb);
    sort_kernel<<<1, 256, 0, stream>>>(tids, pos, row_map, tstart, tcnt);
    conv_all<<<CONV_NT3, 256, 0, stream>>>(W0, W1, Wout, W_head, W0t, W1t, Woutt, Wht);

    dim3 grid(CHUNK / 256, WIDTH / 128, NUM_EXPERTS);
    for (int r0 = 0; r0 < BATCH; r0 += CHUNK) {
        const ushort_t* xc = xb + (size_t)r0 * FEAT;
        mfma_gemm<true ><<<grid, 512, 0, stream>>>(xc, FEAT, 0, W0t, b0, bufA, FEAT);
        mfma_gemm<true ><<<grid, 512, 0, stream>>>(bufA, NUM_EXPERTS * WIDTH, WIDTH, W1t, b1, bufB, WIDTH);
        mfma_gemm<false><<<grid, 512, 0, stream>>>(bufB, NUM_EXPERTS * WIDTH, WIDTH, Woutt, bout, bufA, WIDTH);
        gs_wave_kernel<<<CHUNK / 4, 256, 0, stream>>>(bufA, emb + (size_t)r0 * NUM_EXPERTS,
                                                      pos + r0, featsB);
    }
    head_mfma<<<dim3(6, NUM_TASKS), 256, 0, stream>>>(featsB, row_map, tstart, tcnt,
                                                      Wht, b_head, out);
}